// Round 1
// baseline (132.789 us; speedup 1.0000x reference)
//
#include <hip/hip_runtime.h>
#include <hip/hip_bf16.h>
#include <math.h>

// Problem constants
#define BN 8192      // batch
#define DD 128       // feature dim
#define RPW 64       // rows per wave (4 MFMA n-tiles of 16)
#define NT 4         // RPW/16
#define JSPLIT 16    // column-range splits
#define JRANGE (BN / JSPLIT)   // 512 columns per block

typedef __attribute__((ext_vector_type(8))) short short8;
typedef __attribute__((ext_vector_type(4))) float f32x4;
typedef __attribute__((ext_vector_type(4))) int int4v;

// ---------------- K1: L2-normalize rows, emit bf16 ----------------
__global__ __launch_bounds__(128) void k_norm(const float* __restrict__ feats,
                                              __hip_bfloat16* __restrict__ xbf) {
    const int row = blockIdx.x;
    const int t = threadIdx.x;
    float v = feats[row * DD + t];
    float ss = v * v;
    // reduce within wave (64)
    #pragma unroll
    for (int m = 1; m <= 32; m <<= 1) ss += __shfl_xor(ss, m, 64);
    __shared__ float s2[2];
    if ((t & 63) == 0) s2[t >> 6] = ss;
    __syncthreads();
    const float tot = s2[0] + s2[1];
    const float nrm = fmaxf(sqrtf(tot), 1e-12f);
    xbf[row * DD + t] = __float2bfloat16(v / nrm);
}

// Fragment loader: rows r0..r0+15, k-chunk kc. Same routine for A and B
// operands => any per-lane k-permutation cancels in the contraction.
__device__ inline short8 frag_load(const short* __restrict__ xb, int r0, int kc, int lane) {
    const short* p = xb + (r0 + (lane & 15)) * DD + 32 * kc + 8 * (lane >> 4);
    return *(const short8*)p;
}

// ---------------- K2: pass 1 — per-row max_neg / min_pos partials ----------------
__global__ __launch_bounds__(64) void k_pass1(const short* __restrict__ xb,
                                              const int* __restrict__ lab,
                                              float* __restrict__ mn_p,   // [JSPLIT][BN] max_neg partial
                                              float* __restrict__ mp_p) { // [JSPLIT][BN] min_pos partial
    const int bid = blockIdx.x;
    const int rg = bid / JSPLIT, js = bid % JSPLIT;
    const int i0 = rg * RPW, jb = js * JRANGE;
    const int lane = threadIdx.x;
    const int li = lane & 15, lg = lane >> 4;

    short8 qf[NT][4];
    int labi[NT];
    int irow[NT];
    #pragma unroll
    for (int nt = 0; nt < NT; ++nt) {
        #pragma unroll
        for (int c = 0; c < 4; ++c) qf[nt][c] = frag_load(xb, i0 + 16 * nt, c, lane);
        irow[nt] = i0 + 16 * nt + li;
        labi[nt] = lab[irow[nt]];
    }
    float mn[NT], mp[NT];
    #pragma unroll
    for (int nt = 0; nt < NT; ++nt) { mn[nt] = -1e30f; mp[nt] = 1e30f; }

    for (int jt = 0; jt < JRANGE / 16; ++jt) {
        const int j0 = jb + 16 * jt;
        short8 af[4];
        #pragma unroll
        for (int c = 0; c < 4; ++c) af[c] = frag_load(xb, j0, c, lane);
        const int4v lj = *(const int4v*)(lab + j0 + 4 * lg);
        const int jrow = j0 + 4 * lg;
        #pragma unroll
        for (int nt = 0; nt < NT; ++nt) {
            f32x4 acc = {0.f, 0.f, 0.f, 0.f};
            #pragma unroll
            for (int c = 0; c < 4; ++c)
                acc = __builtin_amdgcn_mfma_f32_16x16x32_bf16(af[c], qf[nt][c], acc, 0, 0, 0);
            #pragma unroll
            for (int r = 0; r < 4; ++r) {
                const float s = acc[r];
                const bool same = (lj[r] == labi[nt]);
                const bool self = (jrow + r == irow[nt]);
                if (same && !self) mp[nt] = fminf(mp[nt], s);
                if (!same)        mn[nt] = fmaxf(mn[nt], s);
            }
        }
    }
    #pragma unroll
    for (int nt = 0; nt < NT; ++nt) {
        mn[nt] = fmaxf(mn[nt], __shfl_xor(mn[nt], 16, 64));
        mn[nt] = fmaxf(mn[nt], __shfl_xor(mn[nt], 32, 64));
        mp[nt] = fminf(mp[nt], __shfl_xor(mp[nt], 16, 64));
        mp[nt] = fminf(mp[nt], __shfl_xor(mp[nt], 32, 64));
    }
    const float wm = (lg == 0) ? mn[0] : (lg == 1) ? mn[1] : (lg == 2) ? mn[2] : mn[3];
    const float wp = (lg == 0) ? mp[0] : (lg == 1) ? mp[1] : (lg == 2) ? mp[2] : mp[3];
    // lane l writes row i0 + l (== i0 + 16*(l>>4) + (l&15))
    mn_p[js * BN + i0 + lane] = wm;
    mp_p[js * BN + i0 + lane] = wp;
}

// ---------------- K3: pass 2 — gated exp-sum partials ----------------
__global__ __launch_bounds__(64) void k_pass2(const short* __restrict__ xb,
                                              const int* __restrict__ lab,
                                              const float* __restrict__ mn_p,
                                              const float* __restrict__ mp_p,
                                              float* __restrict__ ps_p,   // [JSPLIT][BN] pos_sum partial
                                              float* __restrict__ ns_p) { // [JSPLIT][BN] neg_sum partial
    const int bid = blockIdx.x;
    const int rg = bid / JSPLIT, js = bid % JSPLIT;
    const int i0 = rg * RPW, jb = js * JRANGE;
    const int lane = threadIdx.x;
    const int li = lane & 15, lg = lane >> 4;

    short8 qf[NT][4];
    int labi[NT];
    int irow[NT];
    float posthr[NT], negthr[NT];
    #pragma unroll
    for (int nt = 0; nt < NT; ++nt) {
        #pragma unroll
        for (int c = 0; c < 4; ++c) qf[nt][c] = frag_load(xb, i0 + 16 * nt, c, lane);
        irow[nt] = i0 + 16 * nt + li;
        labi[nt] = lab[irow[nt]];
        float mn = -1e30f, mp = 1e30f;
        for (int s = 0; s < JSPLIT; ++s) {
            mn = fmaxf(mn, mn_p[s * BN + irow[nt]]);
            mp = fminf(mp, mp_p[s * BN + irow[nt]]);
        }
        const bool neg_any = (mn > -1e29f);
        const bool pos_any = (mp < 1e29f);
        posthr[nt] = neg_any ? (mn + 0.1f) : -1e30f;  // pos_sel iff sim < posthr
        negthr[nt] = pos_any ? (mp - 0.1f) : 1e30f;   // neg_sel iff sim > negthr
    }
    float ps[NT] = {0.f, 0.f, 0.f, 0.f}, ns[NT] = {0.f, 0.f, 0.f, 0.f};

    for (int jt = 0; jt < JRANGE / 16; ++jt) {
        const int j0 = jb + 16 * jt;
        short8 af[4];
        #pragma unroll
        for (int c = 0; c < 4; ++c) af[c] = frag_load(xb, j0, c, lane);
        const int4v lj = *(const int4v*)(lab + j0 + 4 * lg);
        const int jrow = j0 + 4 * lg;
        #pragma unroll
        for (int nt = 0; nt < NT; ++nt) {
            f32x4 acc = {0.f, 0.f, 0.f, 0.f};
            #pragma unroll
            for (int c = 0; c < 4; ++c)
                acc = __builtin_amdgcn_mfma_f32_16x16x32_bf16(af[c], qf[nt][c], acc, 0, 0, 0);
            #pragma unroll
            for (int r = 0; r < 4; ++r) {
                const float s = acc[r];
                const bool same = (lj[r] == labi[nt]);
                const bool self = (jrow + r == irow[nt]);
                // pos/neg branches are mutually exclusive -> single exp
                const float arg = (same ? -2.0f : 50.0f) * (s - 0.5f);
                const float e = __expf(arg);
                const bool psel = same && !self && (s < posthr[nt]);
                const bool nsel = (!same) && (s > negthr[nt]);
                ps[nt] += psel ? e : 0.0f;
                ns[nt] += nsel ? e : 0.0f;
            }
        }
    }
    #pragma unroll
    for (int nt = 0; nt < NT; ++nt) {
        ps[nt] += __shfl_xor(ps[nt], 16, 64);
        ps[nt] += __shfl_xor(ps[nt], 32, 64);
        ns[nt] += __shfl_xor(ns[nt], 16, 64);
        ns[nt] += __shfl_xor(ns[nt], 32, 64);
    }
    const float wps = (lg == 0) ? ps[0] : (lg == 1) ? ps[1] : (lg == 2) ? ps[2] : ps[3];
    const float wns = (lg == 0) ? ns[0] : (lg == 1) ? ns[1] : (lg == 2) ? ns[2] : ns[3];
    ps_p[js * BN + i0 + lane] = wps;
    ns_p[js * BN + i0 + lane] = wns;
}

// ---------------- K4: finalize — losses + deterministic sum ----------------
__global__ __launch_bounds__(1024) void k_final(const float* __restrict__ ps_p,
                                                const float* __restrict__ ns_p,
                                                float* __restrict__ out) {
    __shared__ float red[16];
    const int t = threadIdx.x;
    float acc = 0.f;
    for (int i = t; i < BN; i += 1024) {
        float ps = 0.f, ns = 0.f;
        #pragma unroll
        for (int s = 0; s < JSPLIT; ++s) {
            ps += ps_p[s * BN + i];
            ns += ns_p[s * BN + i];
        }
        const float pl = (ps > 0.f) ? log1pf(ps) * 0.5f  : 0.f;   // / SCALE_POS
        const float nl = (ns > 0.f) ? log1pf(ns) * 0.02f : 0.f;   // / SCALE_NEG
        acc += pl + nl;
    }
    #pragma unroll
    for (int m = 1; m <= 32; m <<= 1) acc += __shfl_xor(acc, m, 64);
    if ((t & 63) == 0) red[t >> 6] = acc;
    __syncthreads();
    if (t == 0) {
        float tot = 0.f;
        #pragma unroll
        for (int w = 0; w < 16; ++w) tot += red[w];
        out[0] = tot / (float)BN;
    }
}

extern "C" void kernel_launch(void* const* d_in, const int* in_sizes, int n_in,
                              void* d_out, int out_size, void* d_ws, size_t ws_size,
                              hipStream_t stream) {
    const float* feats = (const float*)d_in[0];
    const int* labels = (const int*)d_in[1];   // integer inputs arrive as int32
    float* out = (float*)d_out;

    char* ws = (char*)d_ws;
    __hip_bfloat16* xbf = (__hip_bfloat16*)ws;                    // 2 MB
    float* mn_p = (float*)(ws + 2 * 1024 * 1024);                 // 512 KB
    float* mp_p = mn_p + JSPLIT * BN;                             // 512 KB
    float* ps_p = mp_p + JSPLIT * BN;                             // 512 KB
    float* ns_p = ps_p + JSPLIT * BN;                             // 512 KB

    hipLaunchKernelGGL(k_norm, dim3(BN), dim3(DD), 0, stream, feats, xbf);
    hipLaunchKernelGGL(k_pass1, dim3((BN / RPW) * JSPLIT), dim3(64), 0, stream,
                       (const short*)xbf, labels, mn_p, mp_p);
    hipLaunchKernelGGL(k_pass2, dim3((BN / RPW) * JSPLIT), dim3(64), 0, stream,
                       (const short*)xbf, labels, mn_p, mp_p, ps_p, ns_p);
    hipLaunchKernelGGL(k_final, dim3(1), dim3(1024), 0, stream, ps_p, ns_p, out);
}